// Round 4
// baseline (432.127 us; speedup 1.0000x reference)
//
#include <hip/hip_runtime.h>
#include <stdint.h>
#include <stddef.h>

typedef __attribute__((ext_vector_type(4))) float f32x4;
typedef __attribute__((ext_vector_type(4))) int   i32x4;

constexpr int B = 4, P = 48000, C = 64, NY = 496, NX = 432, CMAP = 16;
constexpr int CT  = C + CMAP;            // 80 output channels
constexpr int X4  = NX / 4;              // 108 float4 groups per full row
constexpr int CQ  = C / 4;               // 16 channel quads
constexpr int GV2 = B * CQ * NY * X4;    // 3,428,352 threads (vox path)
constexpr int NBV = GV2 / 256;           // 13,392 vox blocks (exact)
constexpr int XH  = NX / 2;              // 216: half-row for map LDS tile
constexpr int XH4 = XH / 4;              // 54
constexpr int NBM = B * NY * 2;          // 3,968 map blocks (half-rows)
constexpr size_t PL = (size_t)NY * NX;   // 214,272 channel-plane stride
constexpr size_t OUT_FLOATS = (size_t)B * CT * PL;      // 68,567,040
constexpr size_t OUT_BYTES  = OUT_FLOATS * 4;           // 274,268,160
constexpr int    NQ   = (int)(OUT_FLOATS / 4);          // 17,141,760 quads
constexpr int    CPYG = 2048;                           // copy grid (persistent)
constexpr int    STEP = CPYG * 256;                     // 524,288 threads

// Pass A: build inverse map cell -> point id (cells unique by construction)
__global__ void scatter_inv_kernel(const int* __restrict__ coords,
                                   int* __restrict__ inv) {
    int p = blockIdx.x * blockDim.x + threadIdx.x;
    if (p >= P) return;
    const int4 cd = ((const int4*)coords)[p];     // (b, 0, y, x)
    inv[(cd.x * NY + cd.z) * NX + cd.w] = p;
}

// Fused canvas build (round-0 structure), parameterized destination.
// PLAIN stores: when dst = ws, leave data MALL-resident for the copy pass.
__global__ void __launch_bounds__(256) fused_fill_kernel(
        const float* __restrict__ vox, const float* __restrict__ map,
        const int* __restrict__ inv, float* __restrict__ dst) {
    __shared__ __align__(16) float m_s[CMAP][XH];   // 13.8 KB

    const int blk = blockIdx.x;
    const int tid = threadIdx.x;

    if (blk < NBM) {
        // ---- map path: half-row (b, y, half) ----
        const int half = blk & 1;
        const int by   = blk >> 1;
        const int b    = by / NY;
        const int y    = by - b * NY;
        const int x0   = half * XH;

        const f32x4* map4 = (const f32x4*)map;
        for (int i = tid; i < XH * 4; i += 256) {     // 864 quad-loads
            int xh = i >> 2, q = i & 3;
            f32x4 mv = map4[((size_t)(b * NX + x0 + xh) * NY + y) * 4 + q];
            m_s[q * 4 + 0][xh] = mv.x;
            m_s[q * 4 + 1][xh] = mv.y;
            m_s[q * 4 + 2][xh] = mv.z;
            m_s[q * 4 + 3][xh] = mv.w;
        }
        __syncthreads();

        const size_t out_base = ((size_t)b * CT + C) * PL
                              + (size_t)y * NX + x0;
        for (int idx = tid; idx < CMAP * XH4; idx += 256) {   // 864 stores
            int cm = idx / XH4;
            int x4 = idx - cm * XH4;
            f32x4 v = *(const f32x4*)&m_s[cm][x4 * 4];        // ds_read_b128
            *(f32x4*)(dst + out_base + (size_t)cm * PL + x4 * 4) = v;
        }
    } else {
        // ---- vox path ----
        int g = (blk - NBM) * 256 + tid;              // < GV2, exact
        int x4   = g % X4;
        int rest = g / X4;
        int y   = rest % NY;
        int bcq = rest / NY;                          // b*16 + cq
        int cq  = bcq & (CQ - 1);
        int b   = bcq >> 4;
        int c0  = cq * 4;

        i32x4 p4 = ((const i32x4*)inv)[(b * NY + y) * X4 + x4];

        f32x4 r0 = (f32x4)0.f, r1 = (f32x4)0.f, r2 = (f32x4)0.f, r3 = (f32x4)0.f;
        // pids -1 (empty) or >=0; AND keeps sign bit only if ALL empty (~79%)
        if ((p4.x & p4.y & p4.z & p4.w) >= 0) {
            const f32x4* vox4 = (const f32x4*)vox;    // vox row = 16 f32x4
            if (p4.x >= 0) r0 = vox4[(size_t)p4.x * CQ + cq];
            if (p4.y >= 0) r1 = vox4[(size_t)p4.y * CQ + cq];
            if (p4.z >= 0) r2 = vox4[(size_t)p4.z * CQ + cq];
            if (p4.w >= 0) r3 = vox4[(size_t)p4.w * CQ + cq];
        }

        float* ob = dst + (((size_t)b * CT + c0) * NY + y) * NX + x4 * 4;
        f32x4 s;
        s.x = r0.x; s.y = r1.x; s.z = r2.x; s.w = r3.x;
        *(f32x4*)(ob) = s;
        s.x = r0.y; s.y = r1.y; s.z = r2.y; s.w = r3.y;
        *(f32x4*)(ob + PL) = s;
        s.x = r0.z; s.y = r1.z; s.z = r2.z; s.w = r3.z;
        *(f32x4*)(ob + 2 * PL) = s;
        s.x = r0.w; s.y = r1.w; s.z = r2.w; s.w = r3.w;
        *(f32x4*)(ob + 3 * PL) = s;
    }
}

// Diagnostic/final copy: linear ws -> out. Plain loads (MALL hits from the
// build's plain stores), NT stores (out is write-once). Unroll-2 for MLP.
// Device-wide pattern per loop step = one contiguous 8 MB sweep (fill-like).
__global__ void __launch_bounds__(256) copy_out_kernel(
        const f32x4* __restrict__ ws4, f32x4* __restrict__ out4) {
    int q = blockIdx.x * 256 + threadIdx.x;
    for (; q + STEP < NQ; q += 2 * STEP) {
        f32x4 a = ws4[q];
        f32x4 b = ws4[q + STEP];
        __builtin_nontemporal_store(a, &out4[q]);
        __builtin_nontemporal_store(b, &out4[q + STEP]);
    }
    if (q < NQ) {
        f32x4 a = ws4[q];
        __builtin_nontemporal_store(a, &out4[q]);
    }
}

// Fallback path (no/small workspace): zero canvas region then direct scatter.
__global__ void zero_vox_region_kernel(float* __restrict__ out) {
    int g = blockIdx.x * 256 + threadIdx.x;
    if (g >= B * C * NY * X4) return;
    int x4   = g % X4;
    int rest = g / X4;
    int y  = rest % NY;
    int bc = rest / NY;
    int c  = bc & (C - 1);
    int b  = bc >> 6;
    *(f32x4*)(out + (((size_t)b * CT + c) * NY + y) * NX + x4 * 4) = (f32x4)0.f;
}

__global__ void scatter_direct_kernel(const float* __restrict__ vox,
                                      const int* __restrict__ coords,
                                      float* __restrict__ out) {
    int p = blockIdx.x;
    int c = threadIdx.x;  // 0..63
    const int4 cd = ((const int4*)coords)[p];
    out[(((size_t)cd.x * CT + c) * NY + cd.z) * NX + cd.w] = vox[(size_t)p * C + c];
}

__global__ void map_only_kernel(const float* __restrict__ map,
                                float* __restrict__ out) {
    int g = blockIdx.x * 256 + threadIdx.x;
    if (g >= B * CMAP * NY * NX) return;
    int x    = g % NX;
    int rest = g / NX;
    int y  = rest % NY;
    int bc = rest / NY;
    int cm = bc & (CMAP - 1);
    int b  = bc >> 4;
    out[((size_t)b * CT + C + cm) * PL + (size_t)y * NX + x] =
        map[((size_t)(b * NX + x) * NY + y) * CMAP + cm];
}

extern "C" void kernel_launch(void* const* d_in, const int* in_sizes, int n_in,
                              void* d_out, int out_size, void* d_ws, size_t ws_size,
                              hipStream_t stream) {
    const float* vox    = (const float*)d_in[0];   // (P, 64) float32
    const int*   coords = (const int*)d_in[1];     // (P, 4) int32
    const float* map    = (const float*)d_in[3];   // (B, NX, NY, CMAP) float32
    float* out = (float*)d_out;                    // (B, 80, NY, NX) float32

    const size_t inv_bytes = (size_t)B * NY * NX * sizeof(int);  // 3.43 MB

    if (ws_size >= OUT_BYTES + inv_bytes) {
        // Staged: build full canvas in ws (normal memory), then linear copy.
        float* ws_out = (float*)d_ws;
        int*   inv    = (int*)((char*)d_ws + OUT_BYTES);
        (void)hipMemsetAsync(inv, 0xFF, inv_bytes, stream);      // all -1
        scatter_inv_kernel<<<(P + 255) / 256, 256, 0, stream>>>(coords, inv);
        fused_fill_kernel<<<NBM + NBV, 256, 0, stream>>>(vox, map, inv, ws_out);
        copy_out_kernel<<<CPYG, 256, 0, stream>>>((const f32x4*)ws_out,
                                                  (f32x4*)out);
    } else if (ws_size >= inv_bytes) {
        // Direct round-0 path.
        int* inv = (int*)d_ws;
        (void)hipMemsetAsync(inv, 0xFF, inv_bytes, stream);      // all -1
        scatter_inv_kernel<<<(P + 255) / 256, 256, 0, stream>>>(coords, inv);
        fused_fill_kernel<<<NBM + NBV, 256, 0, stream>>>(vox, map, inv, out);
    } else {
        zero_vox_region_kernel<<<(B * C * NY * X4 + 255) / 256, 256, 0, stream>>>(out);
        scatter_direct_kernel<<<P, 64, 0, stream>>>(vox, coords, out);
        map_only_kernel<<<(B * CMAP * NY * NX + 255) / 256, 256, 0, stream>>>(map, out);
    }
}

// Round 5
// 332.375 us; speedup vs baseline: 1.3001x; 1.3001x over previous
//
#include <hip/hip_runtime.h>
#include <stdint.h>
#include <stddef.h>

typedef __attribute__((ext_vector_type(4))) float f32x4;
typedef __attribute__((ext_vector_type(4))) int   i32x4;

constexpr int B = 4, P = 48000, C = 64, NY = 496, NX = 432, CMAP = 16;
constexpr int CT  = C + CMAP;            // 80 output channels
constexpr int X4  = NX / 4;              // 108 float4 groups per full row
constexpr int CQ  = C / 4;               // 16 channel quads
constexpr int XH  = NX / 2;              // 216: half-row for map LDS tile
constexpr int XH4 = XH / 4;              // 54
constexpr size_t PL = (size_t)NY * NX;   // 214,272 channel-plane stride

// Pass A: build inverse map cell -> point id (cells unique by construction)
__global__ void scatter_inv_kernel(const int* __restrict__ coords,
                                   int* __restrict__ inv) {
    int p = blockIdx.x * blockDim.x + threadIdx.x;
    if (p >= P) return;
    const int4 cd = ((const int4*)coords)[p];     // (b, 0, y, x)
    inv[(cd.x * NY + cd.z) * NX + cd.w] = p;
}

// Pass B: vox dense fill. ALL geometry in the 3-D grid: zero div/mod, b/y/cq
// are SGPR scalars. block=256 covers a y-pair; x4 = tid&127 (108 active).
// Per thread: 1 int4 inv load, <=4 f32x4 gathers, 4 plane-strided NT stores.
__global__ void __launch_bounds__(256) vox_fill_kernel(
        const float* __restrict__ vox, const int* __restrict__ inv,
        float* __restrict__ out) {
    const int x4  = threadIdx.x & 127;
    if (x4 >= X4) return;                          // 20 idle lanes / 128
    const int y   = (blockIdx.y << 1) | (threadIdx.x >> 7);
    const int bcq = blockIdx.z;                    // b*16 + cq
    const int cq  = bcq & (CQ - 1);
    const int b   = bcq >> 4;
    const int c0  = cq * 4;

    i32x4 p4 = ((const i32x4*)inv)[(b * NY + y) * X4 + x4];

    f32x4 r0 = (f32x4)0.f, r1 = (f32x4)0.f, r2 = (f32x4)0.f, r3 = (f32x4)0.f;
    // pids -1 (empty) or >=0; AND keeps sign bit only if ALL empty (~79%)
    if ((p4.x & p4.y & p4.z & p4.w) >= 0) {
        const f32x4* vox4 = (const f32x4*)vox;     // vox row = 16 f32x4
        if (p4.x >= 0) r0 = vox4[(size_t)p4.x * CQ + cq];
        if (p4.y >= 0) r1 = vox4[(size_t)p4.y * CQ + cq];
        if (p4.z >= 0) r2 = vox4[(size_t)p4.z * CQ + cq];
        if (p4.w >= 0) r3 = vox4[(size_t)p4.w * CQ + cq];
    }

    float* ob = out + (((size_t)b * CT + c0) * NY + y) * NX + x4 * 4;
    f32x4 s;
    s.x = r0.x; s.y = r1.x; s.z = r2.x; s.w = r3.x;
    __builtin_nontemporal_store(s, (f32x4*)(ob));
    s.x = r0.y; s.y = r1.y; s.z = r2.y; s.w = r3.y;
    __builtin_nontemporal_store(s, (f32x4*)(ob + PL));
    s.x = r0.z; s.y = r1.z; s.z = r2.z; s.w = r3.z;
    __builtin_nontemporal_store(s, (f32x4*)(ob + 2 * PL));
    s.x = r0.w; s.y = r1.w; s.z = r2.w; s.w = r3.w;
    __builtin_nontemporal_store(s, (f32x4*)(ob + 3 * PL));
}

// Pass C: map transpose, y-pair half-row tiles. Reads are 128 B contiguous
// runs (y-pair x 16cm) per x; all inner indices pow2 shifts/masks.
// LDS [2][16][XH+4]: pad keeps f32x4 rows 16B-aligned, spreads write banks.
__global__ void __launch_bounds__(256) map_tile_kernel(
        const float* __restrict__ map, float* __restrict__ out) {
    __shared__ __align__(16) float m_s[2][CMAP][XH + 4];   // 28.2 KB

    const int tid  = threadIdx.x;
    const int half = blockIdx.x;                  // 0..1
    const int y0   = blockIdx.y << 1;             // y-pair base
    const int b    = blockIdx.z;
    const int x0   = half * XH;

    const f32x4* map4 = (const f32x4*)map;
    // read: 216 xh x (2y x 4q = 128 B run) = 1728 quads, 7 iters
    #pragma unroll
    for (int k = 0; k < 7; ++k) {
        int idx = k * 256 + tid;
        if (idx < XH * 8) {
            int xh = idx >> 3, r = idx & 7, yy = r >> 2, q = r & 3;
            f32x4 mv = map4[((size_t)(b * NX + x0 + xh) * NY + y0 + yy) * 4 + q];
            m_s[yy][q * 4 + 0][xh] = mv.x;
            m_s[yy][q * 4 + 1][xh] = mv.y;
            m_s[yy][q * 4 + 2][xh] = mv.z;
            m_s[yy][q * 4 + 3][xh] = mv.w;
        }
    }
    __syncthreads();

    // write: 2y x 16cm x 64 slots (54 active) = 2048 slots, 8 iters
    const size_t out_base = ((size_t)b * CT + C) * PL + (size_t)y0 * NX + x0;
    #pragma unroll
    for (int k = 0; k < 8; ++k) {
        int idx = k * 256 + tid;
        int sl  = idx & 63;
        int cmy = idx >> 6;                       // 0..31
        int cm  = cmy >> 1, yy = cmy & 1;
        if (sl < XH4) {
            f32x4 v = *(const f32x4*)&m_s[yy][cm][sl * 4];   // ds_read_b128
            __builtin_nontemporal_store(v,
                (f32x4*)(out + out_base + (size_t)cm * PL
                             + (size_t)yy * NX + sl * 4));
        }
    }
}

// Fallback path (no workspace): zero canvas region then direct scatter.
__global__ void zero_vox_region_kernel(float* __restrict__ out) {
    int g = blockIdx.x * 256 + threadIdx.x;
    if (g >= B * C * NY * X4) return;
    int x4   = g % X4;
    int rest = g / X4;
    int y  = rest % NY;
    int bc = rest / NY;
    int c  = bc & (C - 1);
    int b  = bc >> 6;
    *(f32x4*)(out + (((size_t)b * CT + c) * NY + y) * NX + x4 * 4) = (f32x4)0.f;
}

__global__ void scatter_direct_kernel(const float* __restrict__ vox,
                                      const int* __restrict__ coords,
                                      float* __restrict__ out) {
    int p = blockIdx.x;
    int c = threadIdx.x;  // 0..63
    const int4 cd = ((const int4*)coords)[p];
    out[(((size_t)cd.x * CT + c) * NY + cd.z) * NX + cd.w] = vox[(size_t)p * C + c];
}

__global__ void map_only_kernel(const float* __restrict__ map,
                                float* __restrict__ out) {
    int g = blockIdx.x * 256 + threadIdx.x;
    if (g >= B * CMAP * NY * NX) return;
    int x    = g % NX;
    int rest = g / NX;
    int y  = rest % NY;
    int bc = rest / NY;
    int cm = bc & (CMAP - 1);
    int b  = bc >> 4;
    out[((size_t)b * CT + C + cm) * PL + (size_t)y * NX + x] =
        map[((size_t)(b * NX + x) * NY + y) * CMAP + cm];
}

extern "C" void kernel_launch(void* const* d_in, const int* in_sizes, int n_in,
                              void* d_out, int out_size, void* d_ws, size_t ws_size,
                              hipStream_t stream) {
    const float* vox    = (const float*)d_in[0];   // (P, 64) float32
    const int*   coords = (const int*)d_in[1];     // (P, 4) int32
    const float* map    = (const float*)d_in[3];   // (B, NX, NY, CMAP) float32
    float* out = (float*)d_out;                    // (B, 80, NY, NX) float32

    const size_t inv_bytes = (size_t)B * NY * NX * sizeof(int);  // 3.43 MB
    int* inv = (ws_size >= inv_bytes) ? (int*)d_ws : nullptr;

    if (inv) {
        (void)hipMemsetAsync(inv, 0xFF, inv_bytes, stream);      // all -1
        scatter_inv_kernel<<<(P + 255) / 256, 256, 0, stream>>>(coords, inv);
        vox_fill_kernel<<<dim3(1, NY / 2, B * CQ), 256, 0, stream>>>(vox, inv, out);
        map_tile_kernel<<<dim3(2, NY / 2, B), 256, 0, stream>>>(map, out);
    } else {
        zero_vox_region_kernel<<<(B * C * NY * X4 + 255) / 256, 256, 0, stream>>>(out);
        scatter_direct_kernel<<<P, 64, 0, stream>>>(vox, coords, out);
        map_only_kernel<<<(B * CMAP * NY * NX + 255) / 256, 256, 0, stream>>>(map, out);
    }
}